// Round 10
// baseline (1297.135 us; speedup 1.0000x reference)
//
#include <hip/hip_runtime.h>

#define BATCH 32
#define PIX   3072
#define NEU   4096
#define STEPS 99           // reference runs NUM_STEPS-1 = 99 update iterations
#define ETA   (0.001f / 0.03f)
#define NBLK  256          // 256 blocks x 512 thr (proven coop grid, R4-R6)
#define TPB   512
#define SLOT  (BATCH * NEU)          // halves per rotating a-buffer (256 KB)

typedef __bf16 bf16x8 __attribute__((ext_vector_type(8)));
typedef float  f32x4  __attribute__((ext_vector_type(4)));

__device__ __forceinline__ float softt(float u, float lam) {
    return u > lam ? u - lam : (u < -lam ? u + lam : 0.0f);
}

// fp32 -> bf16 round-to-nearest-even
__device__ __forceinline__ unsigned short f2b(float f) {
    unsigned int u = __builtin_bit_cast(unsigned int, f);
    u = (u + 0x7FFFu + ((u >> 16) & 1u)) >> 16;
    return (unsigned short)u;
}

__device__ __forceinline__ bf16x8 ldfrag_g(const unsigned short* p) {
    uint4 v = *(const uint4*)p;
    return __builtin_bit_cast(bf16x8, v);
}

// producer-side drain: this wave's global stores COMPLETE at L3
__device__ __forceinline__ void vm_drain() {
    asm volatile("s_waitcnt vmcnt(0)" ::: "memory");
}

// ---------------------------------------------------------------------------
// φ (fp32 [PIX][NEU]) -> φT (bf16 [NEU][PIX]).  64x64 tiles via LDS.
__global__ void transp(const float* __restrict__ phi, unsigned short* __restrict__ phiT) {
    __shared__ float t[64][65];
    const int n0 = blockIdx.x * 64, p0 = blockIdx.y * 64;
    const int tid = threadIdx.x;
    #pragma unroll
    for (int pass = 0; pass < 4; ++pass) {
        const int r  = pass * 16 + (tid >> 4);
        const int c4 = (tid & 15) * 4;
        float4 v = *(const float4*)(phi + (size_t)(p0 + r) * NEU + n0 + c4);
        t[r][c4 + 0] = v.x; t[r][c4 + 1] = v.y; t[r][c4 + 2] = v.z; t[r][c4 + 3] = v.w;
    }
    __syncthreads();
    #pragma unroll
    for (int pass = 0; pass < 2; ++pass) {
        const int cp = pass * 32 + (tid >> 3);
        const int p8 = (tid & 7) * 8;
        unsigned int w0 = (unsigned int)f2b(t[p8 + 0][cp]) | ((unsigned int)f2b(t[p8 + 1][cp]) << 16);
        unsigned int w1 = (unsigned int)f2b(t[p8 + 2][cp]) | ((unsigned int)f2b(t[p8 + 3][cp]) << 16);
        unsigned int w2 = (unsigned int)f2b(t[p8 + 4][cp]) | ((unsigned int)f2b(t[p8 + 5][cp]) << 16);
        unsigned int w3 = (unsigned int)f2b(t[p8 + 6][cp]) | ((unsigned int)f2b(t[p8 + 7][cp]) << 16);
        uint4 o = make_uint4(w0, w1, w2, w3);
        *(uint4*)(phiT + (size_t)(n0 + cp) * PIX + p0 + p8) = o;
    }
}

// ---------------------------------------------------------------------------
// G = φᵀφ (symmetric, bf16). Upper-triangle blocks only; mirror-store.
__global__ void gemm_G(const unsigned short* __restrict__ phiT, unsigned short* __restrict__ G) {
    if (blockIdx.y > blockIdx.x) return;
    __shared__ __align__(16) unsigned short lds[2][128 * 40];
    const int m0 = blockIdx.y * 128, n0 = blockIdx.x * 128;
    const int tid  = threadIdx.x;
    const int lane = tid & 63, w = tid >> 6;
    const int wm = (w & 1) * 64, wn = (w >> 1) * 64;
    const int q8 = (lane >> 4) * 8, l15 = lane & 15;
    f32x4 acc[4][4] = {};
    for (int k0 = 0; k0 < PIX; k0 += 32) {
        __syncthreads();
        #pragma unroll
        for (int it = 0; it < 2; ++it) {
            const int id = tid + 256 * it;
            const int row = id >> 2, q = id & 3;
            uint4 va = *(const uint4*)(phiT + (size_t)(m0 + row) * PIX + k0 + q * 8);
            *(uint4*)(&lds[0][row * 40 + q * 8]) = va;
            uint4 vb = *(const uint4*)(phiT + (size_t)(n0 + row) * PIX + k0 + q * 8);
            *(uint4*)(&lds[1][row * 40 + q * 8]) = vb;
        }
        __syncthreads();
        bf16x8 af[4], bfr[4];
        #pragma unroll
        for (int i = 0; i < 4; ++i) {
            af[i]  = *(const bf16x8*)(&lds[0][(wm + i * 16 + l15) * 40 + q8]);
            bfr[i] = *(const bf16x8*)(&lds[1][(wn + i * 16 + l15) * 40 + q8]);
        }
        #pragma unroll
        for (int i = 0; i < 4; ++i)
            #pragma unroll
            for (int j = 0; j < 4; ++j)
                acc[i][j] = __builtin_amdgcn_mfma_f32_16x16x32_bf16(af[i], bfr[j], acc[i][j], 0, 0, 0);
    }
    const int q = lane >> 4;
    const bool offdiag = (blockIdx.y != blockIdx.x);
    #pragma unroll
    for (int i = 0; i < 4; ++i)
        #pragma unroll
        for (int j = 0; j < 4; ++j) {
            unsigned short pk[4];
            #pragma unroll
            for (int r = 0; r < 4; ++r) {
                const int gm = m0 + wm + i * 16 + q * 4 + r;
                const int gn = n0 + wn + j * 16 + l15;
                const unsigned short v = f2b(acc[i][j][r]);
                G[(size_t)gm * NEU + gn] = v;
                pk[r] = v;
            }
            if (offdiag) {
                const int gm0 = m0 + wm + i * 16 + q * 4;
                const int gn  = n0 + wn + j * 16 + l15;
                *(ushort4*)(G + (size_t)gn * NEU + gm0) = make_ushort4(pk[0], pk[1], pk[2], pk[3]);
            }
        }
}

// ---------------------------------------------------------------------------
// b = x @ phi; zero the barrier flag array (256 flags, 64-B padded).
// grid 256 (16-col strips), block 512
__global__ void lca_binit(const float* __restrict__ x, const unsigned short* __restrict__ phiT,
                          float* __restrict__ b, unsigned int* __restrict__ arr) {
    __shared__ float red[8 * 512];
    const int tid = threadIdx.x;
    const int lane = tid & 63, w = tid >> 6;
    const int n0 = blockIdx.x * 16;
    const int kbase = w * (PIX / 8);
    const int q8 = (lane >> 4) * 8, l15 = lane & 15;
    if (blockIdx.x == 0)
        for (int i = tid; i < NBLK * 16; i += 512) arr[i] = 0u;
    f32x4 acc[2] = {};
    const unsigned short* Brow = phiT + (size_t)(n0 + l15) * PIX + kbase + q8;
    const float* X0 = x + (size_t)l15 * PIX + kbase + q8;
    const float* X1 = x + (size_t)(16 + l15) * PIX + kbase + q8;
    #pragma unroll 4
    for (int kk = 0; kk < PIX / 8; kk += 32) {
        bf16x8 bg = ldfrag_g(Brow + kk);
        float4 xa0 = *(const float4*)(X0 + kk), xb0 = *(const float4*)(X0 + kk + 4);
        float4 xa1 = *(const float4*)(X1 + kk), xb1 = *(const float4*)(X1 + kk + 4);
        bf16x8 a0, a1;
        a0[0]=(__bf16)xa0.x; a0[1]=(__bf16)xa0.y; a0[2]=(__bf16)xa0.z; a0[3]=(__bf16)xa0.w;
        a0[4]=(__bf16)xb0.x; a0[5]=(__bf16)xb0.y; a0[6]=(__bf16)xb0.z; a0[7]=(__bf16)xb0.w;
        a1[0]=(__bf16)xa1.x; a1[1]=(__bf16)xa1.y; a1[2]=(__bf16)xa1.z; a1[3]=(__bf16)xa1.w;
        a1[4]=(__bf16)xb1.x; a1[5]=(__bf16)xb1.y; a1[6]=(__bf16)xb1.z; a1[7]=(__bf16)xb1.w;
        acc[0] = __builtin_amdgcn_mfma_f32_16x16x32_bf16(a0, bg, acc[0], 0, 0, 0);
        acc[1] = __builtin_amdgcn_mfma_f32_16x16x32_bf16(a1, bg, acc[1], 0, 0, 0);
    }
    const int q = lane >> 4;
    #pragma unroll
    for (int mt = 0; mt < 2; ++mt)
        #pragma unroll
        for (int r = 0; r < 4; ++r)
            red[w * 512 + (mt * 16 + q * 4 + r) * 16 + l15] = acc[mt][r];
    __syncthreads();
    float s = 0.f;
    #pragma unroll
    for (int w8 = 0; w8 < 8; ++w8) s += red[w8 * 512 + tid];
    const int m = tid >> 4, n = n0 + (tid & 15);
    b[(size_t)m * NEU + n] = s;
}

// ---------------------------------------------------------------------------
// publish: lane-pair packs two bf16 into one 4-B agent (L2-bypassing) store
__device__ __forceinline__ void publish(unsigned int* dst, size_t idx, float av, int lane) {
    unsigned int p = f2b(av);
    unsigned int t = (unsigned int)__shfl_xor((int)p, 1, 64);
    if ((lane & 1) == 0)
        __hip_atomic_store(dst + (idx >> 1), p | (t << 16),
                           __ATOMIC_RELAXED, __HIP_MEMORY_SCOPE_AGENT);
}

// ---------------------------------------------------------------------------
// Persistent kernel. 256 blocks x 512 thr (the R4-R6-proven coop grid);
// block owns 16 columns; 8-way k-split.  gf[16] = 64 VGPRs (small enough to
// stay resident under the (512,2) 256-VGPR cap); A staged as ONE 32-load
// burst per step => single L3-latency exposure instead of R7's 8-16.
// Rotating a-buffers (proven R7) => plain pipelined loads, no fences.
__global__ void __launch_bounds__(TPB, 2)
lca_persist(const unsigned short* G, const float* b,
            unsigned short* rot, float* aout, const float* lamp,
            unsigned int* arr) {
    __shared__ float red[8 * 512];
    const int tid  = threadIdx.x;
    const int lane = tid & 63, w = tid >> 6;        // 8 waves
    const int l15  = lane & 15, q = lane >> 4, q8 = q * 8;
    const int n0   = blockIdx.x * 16;               // 16 columns per block
    const int kbase = w * (NEU / 8);                // 512 k per wave

    // --- G fragments: 1 n-tile x 16 k-frags = 64 VGPRs ---
    bf16x8 gf[16];
    #pragma unroll
    for (int f = 0; f < 16; ++f)
        gf[f] = ldfrag_g(G + (size_t)(n0 + l15) * NEU + kbase + f * 32 + q8);

    // --- per-thread state: one output, m = tid>>4, n = n0 + (tid&15) ---
    const int m = tid >> 4;
    const size_t idx = (size_t)m * NEU + n0 + (tid & 15);
    const float bv = b[idx];
    const float lam = lamp[0];

    // step 0 in-register: u1 = ETA*b, a1 = soft(u1); publish into rot[0]
    float uv = ETA * bv;
    float av = softt(uv, lam);

    const size_t aoff0 = (size_t)l15 * NEU + kbase + q8;
    const size_t aoff1 = (size_t)(16 + l15) * NEU + kbase + q8;

    publish((unsigned int*)rot, idx, av, lane);
    vm_drain();
    __syncthreads();                      // all waves' publishes complete
    if (tid == 0)
        __hip_atomic_store(arr + blockIdx.x * 16, 1u,
                           __ATOMIC_RELAXED, __HIP_MEMORY_SCOPE_AGENT);
    if (w < 4) {                          // 4 waves x 64 flags, 1 load/lane
        const int f = w * 64 + lane;
        while (__hip_atomic_load(arr + f * 16, __ATOMIC_RELAXED,
                                 __HIP_MEMORY_SCOPE_AGENT) < 1u)
            __builtin_amdgcn_s_sleep(1);
    }
    __syncthreads();
    asm volatile("" ::: "memory");

    for (int step = 1; step < STEPS; ++step) {       // steps 1..98
        const unsigned short* A = rot + (size_t)(step - 1) * SLOT;

        // ONE burst: all 32 A-fragment loads issued back-to-back
        bf16x8 s0[16], s1[16];
        #pragma unroll
        for (int f = 0; f < 16; ++f) {
            s0[f] = ldfrag_g(A + aoff0 + f * 32);
            s1[f] = ldfrag_g(A + aoff1 + f * 32);
        }
        f32x4 acc0 = {}, acc1 = {};
        #pragma unroll
        for (int f = 0; f < 16; ++f) {
            acc0 = __builtin_amdgcn_mfma_f32_16x16x32_bf16(s0[f], gf[f], acc0, 0, 0, 0);
            acc1 = __builtin_amdgcn_mfma_f32_16x16x32_bf16(s1[f], gf[f], acc1, 0, 0, 0);
        }
        // stage partials: red[w][ m*16 + nn ] (R4-proven layout)
        #pragma unroll
        for (int r = 0; r < 4; ++r) {
            red[w * 512 + (q * 4 + r) * 16 + l15]      = acc0[r];
            red[w * 512 + (16 + q * 4 + r) * 16 + l15] = acc1[r];
        }
        __syncthreads();
        float s = 0.f;
        #pragma unroll
        for (int w8 = 0; w8 < 8; ++w8) s += red[w8 * 512 + tid];

        uv = fmaf(ETA, bv - s + av - uv, uv);
        av = softt(uv, lam);

        if (step == STEPS - 1) {
            aout[idx] = av;
        } else {
            publish((unsigned int*)(rot + (size_t)step * SLOT), idx, av, lane);
            vm_drain();                   // publish complete at L3
            __syncthreads();              // all waves complete; gates red reuse
            const unsigned int e = (unsigned int)(step + 1);
            if (tid == 0)
                __hip_atomic_store(arr + blockIdx.x * 16, e,
                                   __ATOMIC_RELAXED, __HIP_MEMORY_SCOPE_AGENT);
            if (w < 4) {
                const int f = w * 64 + lane;
                while (__hip_atomic_load(arr + f * 16, __ATOMIC_RELAXED,
                                         __HIP_MEMORY_SCOPE_AGENT) < e)
                    __builtin_amdgcn_s_sleep(1);
            }
            __syncthreads();
            asm volatile("" ::: "memory");
        }
    }
}

// ===========================================================================
// Fallback fp32 path (round-1, known correct) for small ws_size / coop failure
// ===========================================================================
__global__ void lca_init_f(const float* __restrict__ x, const float* __restrict__ phi,
                           float* __restrict__ b, float* __restrict__ u,
                           float* __restrict__ a) {
    const int n  = blockIdx.x * 64 + (threadIdx.x & 63);
    const int bi = blockIdx.y * 4 + (threadIdx.x >> 6);
    const float* xr = x + bi * PIX;
    float acc = 0.f;
    #pragma unroll 4
    for (int p = 0; p < PIX; ++p) acc = fmaf(xr[p], phi[p * NEU + n], acc);
    const int idx = bi * NEU + n;
    b[idx] = acc; u[idx] = 0.f; a[idx] = 0.f;
}
__global__ void lca_s_f(const float* __restrict__ a, const float* __restrict__ phi,
                        float* __restrict__ s) {
    const int lane = threadIdx.x & 63, w = threadIdx.x >> 6;
    const int bi = blockIdx.y, p0 = (blockIdx.x * 4 + w) * 8;
    const float* ar = a + bi * NEU;
    float acc[8] = {};
    for (int i = 0; i < NEU / 64; ++i) {
        const int n = i * 64 + lane;
        const float av = ar[n];
        #pragma unroll
        for (int j = 0; j < 8; ++j) acc[j] = fmaf(av, phi[(p0 + j) * NEU + n], acc[j]);
    }
    float out = 0.f;
    #pragma unroll
    for (int j = 0; j < 8; ++j) {
        float v = acc[j];
        v += __shfl_xor(v, 1, 64); v += __shfl_xor(v, 2, 64); v += __shfl_xor(v, 4, 64);
        v += __shfl_xor(v, 8, 64); v += __shfl_xor(v, 16, 64); v += __shfl_xor(v, 32, 64);
        if (lane == j) out = v;
    }
    if (lane < 8) s[bi * PIX + p0 + lane] = out;
}
__global__ void lca_t_f(const float* __restrict__ s, const float* __restrict__ phi,
                        const float* __restrict__ b, float* __restrict__ u,
                        float* __restrict__ a, const float* __restrict__ lamp) {
    __shared__ float ls[8 * 256];
    const int n = blockIdx.x * 64 + (threadIdx.x & 63);
    const int slot = threadIdx.x >> 6;
    const int bb = blockIdx.y * 8 + slot;
    float acc = 0.f;
    for (int c = 0; c < PIX; c += 256) {
        __syncthreads();
        for (int e = threadIdx.x; e < 8 * 256; e += 512) {
            const int r = e >> 8, p = e & 255;
            ls[e] = s[(blockIdx.y * 8 + r) * PIX + c + p];
        }
        __syncthreads();
        const float* lrow = ls + slot * 256;
        #pragma unroll 8
        for (int p = 0; p < 256; ++p) acc = fmaf(lrow[p], phi[(c + p) * NEU + n], acc);
    }
    const float lam = lamp[0];
    const int idx = bb * NEU + n;
    const float uo = u[idx];
    const float du = b[idx] - acc + a[idx] - uo;
    const float un = fmaf(ETA, du, uo);
    u[idx] = un; a[idx] = softt(un, lam);
}

static void run_fallback(const float* x, const float* phi, const float* lamp,
                         float* a, float* fws, hipStream_t stream) {
    float* b = fws;
    float* u = fws + BATCH * NEU;
    float* s = fws + 2 * BATCH * NEU;
    lca_init_f<<<dim3(64, 8), 256, 0, stream>>>(x, phi, b, u, a);
    for (int it = 0; it < STEPS; ++it) {
        lca_s_f<<<dim3(96, 32), 256, 0, stream>>>(a, phi, s);
        lca_t_f<<<dim3(64, 4), 512, 0, stream>>>(s, phi, b, u, a, lamp);
    }
}

// ===========================================================================
extern "C" void kernel_launch(void* const* d_in, const int* in_sizes, int n_in,
                              void* d_out, int out_size, void* d_ws, size_t ws_size,
                              hipStream_t stream) {
    const float* x    = (const float*)d_in[0];
    const float* phi  = (const float*)d_in[1];
    const float* lamp = (const float*)d_in[2];
    float* a = (float*)d_out;
    char* ws = (char*)d_ws;

    // rot region (98 x 256 KB) overlays phiT (24 MB): phiT dead after binit.
    const size_t ROT_BYTES= (size_t)(STEPS - 1) * SLOT * 2;         // 25.69 MB
    const size_t G_OFF    = ROT_BYTES;
    const size_t B_OFF    = G_OFF + (size_t)NEU * NEU * 2;
    const size_t ARR_OFF  = B_OFF + (size_t)BATCH * NEU * 4;
    const size_t NEED     = ARR_OFF + (size_t)NBLK * 64;             // ~59.8 MB

    if (ws_size >= NEED) {
        unsigned short* phiT = (unsigned short*)ws;                  // overlay
        unsigned short* rot  = (unsigned short*)ws;
        unsigned short* G    = (unsigned short*)(ws + G_OFF);
        float*          b    = (float*)(ws + B_OFF);
        unsigned int*   arr  = (unsigned int*)(ws + ARR_OFF);

        transp<<<dim3(NEU / 64, PIX / 64), 256, 0, stream>>>(phi, phiT);
        gemm_G<<<dim3(32, 32), 256, 0, stream>>>(phiT, G);
        lca_binit<<<NBLK, 512, 0, stream>>>(x, phiT, b, arr);

        void* args[6];
        const unsigned short* Gc = G;
        const float* bc = b;
        const float* lc = lamp;
        args[0] = (void*)&Gc;
        args[1] = (void*)&bc;
        args[2] = (void*)&rot;
        args[3] = (void*)&a;
        args[4] = (void*)&lc;
        args[5] = (void*)&arr;
        hipError_t err = hipLaunchCooperativeKernel((const void*)lca_persist,
                                                    dim3(NBLK), dim3(TPB),
                                                    args, 0, stream);
        if (err != hipSuccess) {
            // coop launch rejected (silent-zero failure mode of R8/R9):
            // run the known-correct fp32 path instead.
            run_fallback(x, phi, lamp, a, (float*)d_ws, stream);
        }
    } else {
        run_fallback(x, phi, lamp, a, (float*)d_ws, stream);
    }
}